// Round 12
// baseline (236.238 us; speedup 1.0000x reference)
//
#include <hip/hip_runtime.h>
#include <math.h>

static constexpr float SCALE_F = (float)(2.0 * 28.0 * 0.32178);

__device__ __forceinline__ float eluf(float x){ return x > 0.f ? x : expm1f(x); }

// Wave-local LDS visibility: lockstep wave + drain LDS queue (no s_barrier).
__device__ __forceinline__ void wave_sync(){
    __builtin_amdgcn_wave_barrier();
    asm volatile("s_waitcnt lgkmcnt(0)" ::: "memory");
    __builtin_amdgcn_wave_barrier();
}

// K1: sentinels for member scatter + gpart zero (must precede prep's atomics)
__global__ void initk(int* __restrict__ mlo1, int* __restrict__ mhi1, int C1,
                      int* __restrict__ mlo2, int* __restrict__ mhi2, int C2,
                      float* __restrict__ gpart){
    int i = blockIdx.x*blockDim.x + threadIdx.x, gs = gridDim.x*blockDim.x;
    for (int c = i; c < C1; c += gs){ mlo1[c] = 0x7FFFFFFF; mhi1[c] = -1; }
    for (int c = i; c < C2; c += gs){ mlo2[c] = 0x7FFFFFFF; mhi2[c] = -1; }
    for (int k = i; k < 64*64; k += gs) gpart[k] = 0.f;
}

// K2: pack {pos,x} float4; build 3 rowptrs; scatter cluster members (<=2 per cluster)
__global__ void prep_kernel(const float* __restrict__ x, const float* __restrict__ pos, int N,
    const int* __restrict__ ei1, int E1, const int* __restrict__ ei2, int E2, int C1,
    const int* __restrict__ ei3, int E3, int C2,
    const int* __restrict__ cl1, const int* __restrict__ cl2,
    int* __restrict__ rp1, int* __restrict__ rp2, int* __restrict__ rp3,
    int* __restrict__ mlo1, int* __restrict__ mhi1, int* __restrict__ mlo2, int* __restrict__ mhi2,
    float4* __restrict__ xp1)
{
    int i0 = blockIdx.x*blockDim.x + threadIdx.x, gs = gridDim.x*blockDim.x;
    for (int i = i0; i < N; i += gs){
        xp1[i] = make_float4(pos[2*i], pos[2*i+1], x[i], 0.f);
        int c = cl1[i];
        atomicMin(&mlo1[c], i); atomicMax(&mhi1[c], i);
    }
    for (int i = i0; i < C1; i += gs){
        int c = cl2[i];
        atomicMin(&mlo2[c], i); atomicMax(&mhi2[c], i);
    }
    int nrp = N + C1 + C2 + 3;
    for (int i = i0; i < nrp; i += gs){
        const int* rows; int E, n; int* rp;
        if (i <= N)            { rows = ei1; E = E1; n = i;            rp = rp1 + n; }
        else if (i <= N+1+C1)  { rows = ei2; E = E2; n = i - (N+1);    rp = rp2 + n; }
        else                   { rows = ei3; E = E3; n = i - (N+C1+2); rp = rp3 + n; }
        int lo = 0, hi = E;
        while (lo < hi){ int m = (lo+hi) >> 1; if (rows[m] < n) lo = m+1; else hi = m; }
        *rp = lo;
    }
}

// K3: layer1 (I=1,O=32). Quarter-wave per node; PLAIN coalesced h1 writes (no atomics).
__global__ __launch_bounds__(256) void l1_kernel(const float4* __restrict__ xp1,
    const int* __restrict__ ei1, int E1, const int* __restrict__ rp1,
    const float* __restrict__ g1, const float* __restrict__ mu1, const float* __restrict__ sg1,
    const float* __restrict__ rt1, const float* __restrict__ b1,
    float* __restrict__ h1, int N)
{
    int t = threadIdx.x;
    int lane = t & 63, wv = t >> 6;
    int q = lane >> 4, il = lane & 15;
    int n = (blockIdx.x*4 + wv)*4 + q;
    if (n >= N) return;
    const int* cols = ei1 + E1;
    float mx[9], my[9], ivx[9], ivy[9];
    #pragma unroll
    for (int k = 0; k < 9; k++){
        mx[k] = mu1[2*k]; my[k] = mu1[2*k+1];
        float sx = sg1[2*k], sy = sg1[2*k+1];
        ivx[k] = 1.f/(sx*sx); ivy[k] = 1.f/(sy*sy);
    }
    float4 me = xp1[n];
    float px = me.x, py = me.y, xn = me.z;
    int e0 = rp1[n], e1 = rp1[n+1];
    float s[9] = {0.f,0.f,0.f,0.f,0.f,0.f,0.f,0.f,0.f};
    for (int e = e0 + il; e < e1; e += 16){
        int j = cols[e];
        float4 pj = xp1[j];
        float ux = (px - pj.x)/SCALE_F + 0.5f;
        float uy = (py - pj.y)/SCALE_F + 0.5f;
        #pragma unroll
        for (int k = 0; k < 9; k++){
            float dx = ux - mx[k], dy = uy - my[k];
            s[k] += pj.z * expf(-0.5f*(dx*dx*ivx[k] + dy*dy*ivy[k]));
        }
    }
    #pragma unroll
    for (int off = 8; off > 0; off >>= 1){
        #pragma unroll
        for (int k = 0; k < 9; k++) s[k] += __shfl_xor(s[k], off, 16);
    }
    float inv = 1.f / (float)max(e1 - e0, 1);
    #pragma unroll
    for (int oo = 0; oo < 2; oo++){
        int o = il + oo*16;
        float acc = 0.f;
        #pragma unroll
        for (int k = 0; k < 9; k++) acc += g1[k*32+o] * s[k];
        h1[(size_t)n*32 + o] = eluf(acc*inv + xn*rt1[o] + b1[o]);
    }
}

// K4: pool1 — h2[c] = max over <=2 members of h1; pos2 = member mean (gather, no atomics)
__global__ void pool1_kernel(const float* __restrict__ h1, const float4* __restrict__ xp1,
    const int* __restrict__ mlo1, const int* __restrict__ mhi1,
    float* __restrict__ h2, float4* __restrict__ pos2s4, int C1)
{
    int i0 = blockIdx.x*blockDim.x + threadIdx.x, gs = gridDim.x*blockDim.x;
    for (int idx = i0; idx < C1*32; idx += gs){
        int c = idx >> 5, i = idx & 31;
        h2[idx] = fmaxf(h1[(size_t)mlo1[c]*32 + i], h1[(size_t)mhi1[c]*32 + i]);
    }
    for (int c = i0; c < C1; c += gs){
        int a = mlo1[c], b = mhi1[c];
        float4 pa = xp1[a];
        float px, py;
        if (a == b){ px = pa.x; py = pa.y; }
        else { float4 pb = xp1[b]; px = (pa.x + pb.x)/2.f; py = (pa.y + pb.y)/2.f; }
        pos2s4[c] = make_float4(px, py, 0.f, 0.f);
    }
}

// K5: layer2 gather — wave per node, ZERO block barriers, writes S2[n][288]
__global__ __launch_bounds__(256) void l2a_kernel(const float* __restrict__ h2,
    const float4* __restrict__ pos2s4,
    const int* __restrict__ ei2, int E2, const int* __restrict__ rp2,
    const float* __restrict__ mu2, const float* __restrict__ sg2,
    float* __restrict__ S2, int C1)
{
    __shared__ __align__(16) float wbuf[4][768];  // Wc padded [64][12]
    __shared__ int jcs[4][64];
    int t = threadIdx.x, l = t & 63, w = t >> 6;
    int n = blockIdx.x*4 + w;
    if (n >= C1) return;
    const int* cols = ei2 + E2;
    float mx[9], my[9], ivx[9], ivy[9];
    #pragma unroll
    for (int k = 0; k < 9; k++){
        mx[k] = mu2[2*k]; my[k] = mu2[2*k+1];
        float sx = sg2[2*k], sy = sg2[2*k+1];
        ivx[k] = 1.f/(sx*sx); ivy[k] = 1.f/(sy*sy);
    }
    float4 pm = pos2s4[n];
    float px = pm.x, py = pm.y;
    int e0 = rp2[n], e1 = rp2[n+1];
    int i = l & 31, half = l >> 5;
    float sacc[9] = {0.f,0.f,0.f,0.f,0.f,0.f,0.f,0.f,0.f};
    for (int base = e0; base < e1; base += 64){
        int ne = min(64, e1 - base);
        if (l < ne){
            int j = cols[base + l];
            jcs[w][l] = j;
            float4 pj = pos2s4[j];
            float ux = (px - pj.x)/SCALE_F + 0.5f;
            float uy = (py - pj.y)/SCALE_F + 0.5f;
            float wk[9];
            #pragma unroll
            for (int k = 0; k < 9; k++){
                float dx = ux - mx[k], dy = uy - my[k];
                wk[k] = expf(-0.5f*(dx*dx*ivx[k] + dy*dy*ivy[k]));
            }
            *(float4*)&wbuf[w][l*12]     = make_float4(wk[0], wk[1], wk[2], wk[3]);
            *(float4*)&wbuf[w][l*12 + 4] = make_float4(wk[4], wk[5], wk[6], wk[7]);
            wbuf[w][l*12 + 8] = wk[8];
        }
        wave_sync();
        int jj = half;
        for (; jj + 6 < ne; jj += 8){
            int j0 = jcs[w][jj],   j1 = jcs[w][jj+2];
            int j2 = jcs[w][jj+4], j3 = jcs[w][jj+6];
            float x0 = h2[(size_t)j0*32 + i];
            float x1 = h2[(size_t)j1*32 + i];
            float x2 = h2[(size_t)j2*32 + i];
            float x3 = h2[(size_t)j3*32 + i];
            #pragma unroll
            for (int u = 0; u < 4; u++){
                int jc = jj + 2*u;
                float xv = (u==0)?x0:(u==1)?x1:(u==2)?x2:x3;
                float4 wa = *(const float4*)&wbuf[w][jc*12];
                float4 wb = *(const float4*)&wbuf[w][jc*12 + 4];
                float  w8 = wbuf[w][jc*12 + 8];
                sacc[0] += xv*wa.x; sacc[1] += xv*wa.y; sacc[2] += xv*wa.z; sacc[3] += xv*wa.w;
                sacc[4] += xv*wb.x; sacc[5] += xv*wb.y; sacc[6] += xv*wb.z; sacc[7] += xv*wb.w;
                sacc[8] += xv*w8;
            }
        }
        for (; jj < ne; jj += 2){
            int j = jcs[w][jj];
            float xv = h2[(size_t)j*32 + i];
            float4 wa = *(const float4*)&wbuf[w][jj*12];
            float4 wb = *(const float4*)&wbuf[w][jj*12 + 4];
            float  w8 = wbuf[w][jj*12 + 8];
            sacc[0] += xv*wa.x; sacc[1] += xv*wa.y; sacc[2] += xv*wa.z; sacc[3] += xv*wa.w;
            sacc[4] += xv*wb.x; sacc[5] += xv*wb.y; sacc[6] += xv*wb.z; sacc[7] += xv*wb.w;
            sacc[8] += xv*w8;
        }
        wave_sync();
    }
    #pragma unroll
    for (int k = 0; k < 9; k++) sacc[k] += __shfl_xor(sacc[k], 32, 64);
    if (l < 32){
        #pragma unroll
        for (int k = 0; k < 9; k++) S2[(size_t)n*288 + l*9 + k] = sacc[k];
    }
}

// K6: layer2 finish — wave per node, stream g2 columns (coalesced), root+bias+elu
__global__ __launch_bounds__(256) void l2b_kernel(const float* __restrict__ S2,
    const float* __restrict__ h2, const int* __restrict__ rp2,
    const float* __restrict__ g2, const float* __restrict__ rt2, const float* __restrict__ b2,
    float* __restrict__ h2out, int C1)
{
    __shared__ __align__(16) float sbuf[4][288];
    __shared__ __align__(16) float xns[4][32];
    int t = threadIdx.x, l = t & 63, w = t >> 6;
    int n = blockIdx.x*4 + w;
    if (n >= C1) return;
    const float4* srow = (const float4*)(S2 + (size_t)n*288);  // 72 float4, 16B aligned
    *(float4*)&sbuf[w][l*4] = srow[l];                         // 64 float4
    if (l < 8) *(float4*)&sbuf[w][(64+l)*4] = srow[64+l];      // remaining 8 float4
    if (l < 32) xns[w][l] = h2[(size_t)n*32 + l];
    wave_sync();
    const float* gcol = g2 + l;
    float acc = 0.f;
    #pragma unroll 4
    for (int qq = 0; qq < 36; qq++){
        int ib = qq*8;
        float g0 = gcol[(ib+0)*64], g1v = gcol[(ib+1)*64];
        float g2v = gcol[(ib+2)*64], g3 = gcol[(ib+3)*64];
        float g4 = gcol[(ib+4)*64], g5 = gcol[(ib+5)*64];
        float g6 = gcol[(ib+6)*64], g7 = gcol[(ib+7)*64];
        float4 sa = *(const float4*)&sbuf[w][ib];
        float4 sb = *(const float4*)&sbuf[w][ib+4];
        acc += g0*sa.x; acc += g1v*sa.y; acc += g2v*sa.z; acc += g3*sa.w;
        acc += g4*sb.x; acc += g5*sb.y; acc += g6*sb.z; acc += g7*sb.w;
    }
    const float* rcol = rt2 + l;
    float racc = 0.f;
    #pragma unroll 2
    for (int qq = 0; qq < 4; qq++){
        int ib = qq*8;
        float4 xa = *(const float4*)&xns[w][ib];
        float4 xb = *(const float4*)&xns[w][ib+4];
        racc += rcol[(ib+0)*64]*xa.x; racc += rcol[(ib+1)*64]*xa.y;
        racc += rcol[(ib+2)*64]*xa.z; racc += rcol[(ib+3)*64]*xa.w;
        racc += rcol[(ib+4)*64]*xb.x; racc += rcol[(ib+5)*64]*xb.y;
        racc += rcol[(ib+6)*64]*xb.z; racc += rcol[(ib+7)*64]*xb.w;
    }
    int deg = rp2[n+1] - rp2[n];
    float inv = 1.f / (float)max(deg, 1);
    h2out[(size_t)n*64 + l] = eluf(acc*inv + racc + b2[l]);
}

// K7: pool2 — h3[c] = max over <=2 members of h2out; pos3 = member mean of pos2
__global__ void pool2_kernel(const float* __restrict__ h2out, const float4* __restrict__ pos2s4,
    const int* __restrict__ mlo2, const int* __restrict__ mhi2,
    float* __restrict__ h3, float4* __restrict__ pos3s4, int C2)
{
    int i0 = blockIdx.x*blockDim.x + threadIdx.x, gs = gridDim.x*blockDim.x;
    for (int idx = i0; idx < C2*64; idx += gs){
        int c = idx >> 6, i = idx & 63;
        h3[idx] = fmaxf(h2out[(size_t)mlo2[c]*64 + i], h2out[(size_t)mhi2[c]*64 + i]);
    }
    for (int c = i0; c < C2; c += gs){
        int a = mlo2[c], b = mhi2[c];
        float4 pa = pos2s4[a];
        float px, py;
        if (a == b){ px = pa.x; py = pa.y; }
        else { float4 pb = pos2s4[b]; px = (pa.x + pb.x)/2.f; py = (pa.y + pb.y)/2.f; }
        pos3s4[c] = make_float4(px, py, 0.f, 0.f);
    }
}

// K8: layer3 gather — wave per node, all 64 lanes own i=l, writes S3[n][576]
__global__ __launch_bounds__(256) void l3a_kernel(const float* __restrict__ h3,
    const float4* __restrict__ pos3s4,
    const int* __restrict__ ei3, int E3, const int* __restrict__ rp3,
    const float* __restrict__ mu3, const float* __restrict__ sg3,
    float* __restrict__ S3, int C2)
{
    __shared__ __align__(16) float wbuf[4][768];
    __shared__ int jcs[4][64];
    int t = threadIdx.x, l = t & 63, w = t >> 6;
    int n = blockIdx.x*4 + w;
    if (n >= C2) return;
    const int* cols = ei3 + E3;
    float mx[9], my[9], ivx[9], ivy[9];
    #pragma unroll
    for (int k = 0; k < 9; k++){
        mx[k] = mu3[2*k]; my[k] = mu3[2*k+1];
        float sx = sg3[2*k], sy = sg3[2*k+1];
        ivx[k] = 1.f/(sx*sx); ivy[k] = 1.f/(sy*sy);
    }
    float4 pm = pos3s4[n];
    float px = pm.x, py = pm.y;
    int e0 = rp3[n], e1 = rp3[n+1];
    float sacc[9] = {0.f,0.f,0.f,0.f,0.f,0.f,0.f,0.f,0.f};
    for (int base = e0; base < e1; base += 64){
        int ne = min(64, e1 - base);
        if (l < ne){
            int j = cols[base + l];
            jcs[w][l] = j;
            float4 pj = pos3s4[j];
            float ux = (px - pj.x)/SCALE_F + 0.5f;
            float uy = (py - pj.y)/SCALE_F + 0.5f;
            float wk[9];
            #pragma unroll
            for (int k = 0; k < 9; k++){
                float dx = ux - mx[k], dy = uy - my[k];
                wk[k] = expf(-0.5f*(dx*dx*ivx[k] + dy*dy*ivy[k]));
            }
            *(float4*)&wbuf[w][l*12]     = make_float4(wk[0], wk[1], wk[2], wk[3]);
            *(float4*)&wbuf[w][l*12 + 4] = make_float4(wk[4], wk[5], wk[6], wk[7]);
            wbuf[w][l*12 + 8] = wk[8];
        }
        wave_sync();
        int jj = 0;
        for (; jj + 3 < ne; jj += 4){
            int j0 = jcs[w][jj],   j1 = jcs[w][jj+1];
            int j2 = jcs[w][jj+2], j3 = jcs[w][jj+3];
            float x0 = h3[(size_t)j0*64 + l];
            float x1 = h3[(size_t)j1*64 + l];
            float x2 = h3[(size_t)j2*64 + l];
            float x3 = h3[(size_t)j3*64 + l];
            #pragma unroll
            for (int u = 0; u < 4; u++){
                int jc = jj + u;
                float xv = (u==0)?x0:(u==1)?x1:(u==2)?x2:x3;
                float4 wa = *(const float4*)&wbuf[w][jc*12];
                float4 wb = *(const float4*)&wbuf[w][jc*12 + 4];
                float  w8 = wbuf[w][jc*12 + 8];
                sacc[0] += xv*wa.x; sacc[1] += xv*wa.y; sacc[2] += xv*wa.z; sacc[3] += xv*wa.w;
                sacc[4] += xv*wb.x; sacc[5] += xv*wb.y; sacc[6] += xv*wb.z; sacc[7] += xv*wb.w;
                sacc[8] += xv*w8;
            }
        }
        for (; jj < ne; jj++){
            int j = jcs[w][jj];
            float xv = h3[(size_t)j*64 + l];
            float4 wa = *(const float4*)&wbuf[w][jj*12];
            float4 wb = *(const float4*)&wbuf[w][jj*12 + 4];
            float  w8 = wbuf[w][jj*12 + 8];
            sacc[0] += xv*wa.x; sacc[1] += xv*wa.y; sacc[2] += xv*wa.z; sacc[3] += xv*wa.w;
            sacc[4] += xv*wb.x; sacc[5] += xv*wb.y; sacc[6] += xv*wb.z; sacc[7] += xv*wb.w;
            sacc[8] += xv*w8;
        }
        wave_sync();
    }
    #pragma unroll
    for (int k = 0; k < 9; k++) S3[(size_t)n*576 + l*9 + k] = sacc[k];
}

// K9: layer3 finish — stream g3 columns + root + elu, accumulate gpart partials
__global__ __launch_bounds__(256) void l3b_kernel(const float* __restrict__ S3,
    const float* __restrict__ h3, const int* __restrict__ rp3,
    const float* __restrict__ g3, const float* __restrict__ rt3, const float* __restrict__ b3,
    float* __restrict__ gpart, int C2)
{
    __shared__ __align__(16) float sbuf[4][576];
    __shared__ __align__(16) float xns[4][64];
    int t = threadIdx.x, l = t & 63, w = t >> 6;
    int n = blockIdx.x*4 + w;
    if (n >= C2) return;
    const float4* srow = (const float4*)(S3 + (size_t)n*576);  // 144 float4
    *(float4*)&sbuf[w][l*4] = srow[l];
    *(float4*)&sbuf[w][(64+l)*4] = srow[64+l];
    if (l < 16) *(float4*)&sbuf[w][(128+l)*4] = srow[128+l];
    xns[w][l] = h3[(size_t)n*64 + l];
    wave_sync();
    const float* gcol = g3 + l;
    float acc = 0.f;
    #pragma unroll 4
    for (int qq = 0; qq < 72; qq++){
        int ib = qq*8;
        float g0 = gcol[(ib+0)*64], g1v = gcol[(ib+1)*64];
        float g2v = gcol[(ib+2)*64], g3v = gcol[(ib+3)*64];
        float g4 = gcol[(ib+4)*64], g5 = gcol[(ib+5)*64];
        float g6 = gcol[(ib+6)*64], g7 = gcol[(ib+7)*64];
        float4 sa = *(const float4*)&sbuf[w][ib];
        float4 sb = *(const float4*)&sbuf[w][ib+4];
        acc += g0*sa.x; acc += g1v*sa.y; acc += g2v*sa.z; acc += g3v*sa.w;
        acc += g4*sb.x; acc += g5*sb.y; acc += g6*sb.z; acc += g7*sb.w;
    }
    const float* rcol = rt3 + l;
    float racc = 0.f;
    #pragma unroll 2
    for (int qq = 0; qq < 8; qq++){
        int ib = qq*8;
        float4 xa = *(const float4*)&xns[w][ib];
        float4 xb = *(const float4*)&xns[w][ib+4];
        racc += rcol[(ib+0)*64]*xa.x; racc += rcol[(ib+1)*64]*xa.y;
        racc += rcol[(ib+2)*64]*xa.z; racc += rcol[(ib+3)*64]*xa.w;
        racc += rcol[(ib+4)*64]*xb.x; racc += rcol[(ib+5)*64]*xb.y;
        racc += rcol[(ib+6)*64]*xb.z; racc += rcol[(ib+7)*64]*xb.w;
    }
    int deg = rp3[n+1] - rp3[n];
    float inv = 1.f / (float)max(deg, 1);
    float h = eluf(acc*inv + racc + b3[l]);
    atomicAdd(&gpart[(size_t)(n & 63)*64 + l], h);
}

__global__ void final_kernel(const float* __restrict__ gpart, const float* __restrict__ fw,
                             const float* __restrict__ fb, float* __restrict__ out, int C2){
    __shared__ float gs[64];
    __shared__ float red[2*64];
    int t = threadIdx.x;           // 128 threads
    int o = t & 63, h = t >> 6;
    float a = 0.f;
    for (int p = h*32; p < h*32 + 32; p++) a += gpart[p*64 + o];
    red[h*64 + o] = a;
    __syncthreads();
    if (t < 64) gs[t] = (red[t] + red[64+t]) / (float)C2;
    __syncthreads();
    float acc = fb[t];
    for (int o2 = 0; o2 < 64; o2++) acc += gs[o2] * fw[o2*128 + t];
    out[t] = acc;
}

extern "C" void kernel_launch(void* const* d_in, const int* in_sizes, int n_in,
                              void* d_out, int out_size, void* d_ws, size_t ws_size,
                              hipStream_t stream)
{
    const float* x    = (const float*)d_in[0];
    const float* pos  = (const float*)d_in[1];
    const int*   ei1  = (const int*)d_in[2];
    const int*   cl1  = (const int*)d_in[3];
    const int*   ei2  = (const int*)d_in[4];
    const int*   cl2  = (const int*)d_in[5];
    const int*   ei3  = (const int*)d_in[6];
    const float* g1   = (const float*)d_in[8];
    const float* mu1  = (const float*)d_in[9];
    const float* sg1  = (const float*)d_in[10];
    const float* rt1  = (const float*)d_in[11];
    const float* b1   = (const float*)d_in[12];
    const float* g2   = (const float*)d_in[13];
    const float* mu2  = (const float*)d_in[14];
    const float* sg2  = (const float*)d_in[15];
    const float* rt2  = (const float*)d_in[16];
    const float* b2   = (const float*)d_in[17];
    const float* g3   = (const float*)d_in[18];
    const float* mu3  = (const float*)d_in[19];
    const float* sg3  = (const float*)d_in[20];
    const float* rt3  = (const float*)d_in[21];
    const float* b3   = (const float*)d_in[22];
    const float* fw   = (const float*)d_in[23];
    const float* fb   = (const float*)d_in[24];
    float* out = (float*)d_out;

    const int N  = in_sizes[0];
    const int E1 = in_sizes[2] / 2;
    const int C1 = in_sizes[5];
    const int E2 = in_sizes[4] / 2;
    const int C2 = in_sizes[7];
    const int E3 = in_sizes[6] / 2;

    // workspace layout (floats); float4 regions first (16B aligned)
    float* w = (float*)d_ws;
    size_t off = 0;
    float4* xp1    = (float4*)(w + off); off += (size_t)4*N;
    float4* pos2s4 = (float4*)(w + off); off += (size_t)4*C1;
    float4* pos3s4 = (float4*)(w + off); off += (size_t)4*C2;
    size_t sbig = (size_t)288*C1 > (size_t)576*C2 ? (size_t)288*C1 : (size_t)576*C2;
    float* Sbig = w + off; off += sbig;            // S2 and S3 alias (disjoint lifetimes)
    float* h1    = w + off; off += (size_t)32*N;
    float* h2    = w + off; off += (size_t)32*C1;
    float* h2out = w + off; off += (size_t)64*C1;
    float* h3    = w + off; off += (size_t)64*C2;
    float* gpart = w + off; off += 64*64;
    int* rp1  = (int*)(w + off); off += (size_t)N + 1;
    int* rp2  = (int*)(w + off); off += (size_t)C1 + 1;
    int* rp3  = (int*)(w + off); off += (size_t)C2 + 1;
    int* mlo1 = (int*)(w + off); off += (size_t)C1;
    int* mhi1 = (int*)(w + off); off += (size_t)C1;
    int* mlo2 = (int*)(w + off); off += (size_t)C2;
    int* mhi2 = (int*)(w + off); off += (size_t)C2;

    initk<<<dim3(64), dim3(256), 0, stream>>>(mlo1, mhi1, C1, mlo2, mhi2, C2, gpart);
    prep_kernel<<<dim3(512), dim3(256), 0, stream>>>(x, pos, N,
        ei1, E1, ei2, E2, C1, ei3, E3, C2, cl1, cl2,
        rp1, rp2, rp3, mlo1, mhi1, mlo2, mhi2, xp1);
    l1_kernel<<<dim3((N + 15)/16), dim3(256), 0, stream>>>(xp1, ei1, E1, rp1,
        g1, mu1, sg1, rt1, b1, h1, N);
    pool1_kernel<<<dim3(1024), dim3(256), 0, stream>>>(h1, xp1, mlo1, mhi1, h2, pos2s4, C1);
    l2a_kernel<<<dim3((C1 + 3)/4), dim3(256), 0, stream>>>(h2, pos2s4, ei2, E2, rp2,
        mu2, sg2, Sbig, C1);
    l2b_kernel<<<dim3((C1 + 3)/4), dim3(256), 0, stream>>>(Sbig, h2, rp2,
        g2, rt2, b2, h2out, C1);
    pool2_kernel<<<dim3(512), dim3(256), 0, stream>>>(h2out, pos2s4, mlo2, mhi2, h3, pos3s4, C2);
    l3a_kernel<<<dim3((C2 + 3)/4), dim3(256), 0, stream>>>(h3, pos3s4, ei3, E3, rp3,
        mu3, sg3, Sbig, C2);
    l3b_kernel<<<dim3((C2 + 3)/4), dim3(256), 0, stream>>>(Sbig, h3, rp3,
        g3, rt3, b3, gpart, C2);
    final_kernel<<<dim3(1), dim3(128), 0, stream>>>(gpart, fw, fb, out, C2);
}